// Round 13
// baseline (122.046 us; speedup 1.0000x reference)
//
#include <hip/hip_runtime.h>

typedef unsigned short u16;
typedef unsigned int u32;
typedef __attribute__((ext_vector_type(8))) short short8;   // 8 bf16 (4 VGPRs)
typedef __attribute__((ext_vector_type(4))) float f32x4;

// ws layout (bytes), all 16B-aligned
#define WS_W3T  0        // float[96]  (W3 augmented: [90]=b3, [91..95]=0)
#define WS_W0F  384      // u16[6][6*64*8]  per-o L1 fragments w/ bias rows k=5..9
#define WS_W1F  37248    // u16[18*64*8]
#define WS_W2F  55680    // u16[18*64*8]   (ends 74112)

__device__ __forceinline__ u16 f2b(float f) {  // RNE f32 -> bf16 (prep only)
  union { u32 i; float f; } v; v.f = f;
  u32 i = v.i;
  return (u16)((i + 0x7FFFu + ((i >> 16) & 1u)) >> 16);
}

// 3-op bf16 pair pack (round-half-up + v_perm). Verified R7.
__device__ __forceinline__ u32 pk2(float a, float b) {  // a -> low, b -> high
  u32 ia = __float_as_uint(a) + 0x8000u;
  u32 ib = __float_as_uint(b) + 0x8000u;
  return __builtin_amdgcn_perm(ib, ia, 0x07060302u);
}

// Compiler-only memory barrier: pins ds_reads into their chunks.
__device__ __forceinline__ void lds_compiler_fence() {
  asm volatile("" ::: "memory");
}

// prep: identical math to R8-R12 (verified absmax 7.8e-3).
__global__ void prep_kernel(const float* __restrict__ ac, const float* __restrict__ W0,
                            const float* __restrict__ b0, const float* __restrict__ W1,
                            const float* __restrict__ b1, const float* __restrict__ W2,
                            const float* __restrict__ b2, const float* __restrict__ W3,
                            const float* __restrict__ b3,
                            float* __restrict__ w3t, u16* __restrict__ W0f,
                            u16* __restrict__ W1f, u16* __restrict__ W2f) {
  int tid = blockIdx.x * blockDim.x + threadIdx.x;
  int nth = gridDim.x * blockDim.x;
  for (int i = tid; i < 96; i += nth)
    w3t[i] = (i < 90) ? W3[i] : ((i == 90) ? b3[0] : 0.0f);
  for (int i = tid; i < 6 * 6 * 64 * 8; i += nth) {
    int o = i / 3072, rem = i % 3072;
    int t = rem >> 9, lane = (rem >> 3) & 63, jj = rem & 7;
    int q = lane >> 4, m = lane & 15;
    int k = q * 8 + jj;
    int u = t * 16 + m;
    u16 v = 0;
    if (k < 5) {
      const int rowmap[5] = {5, 0, 1, 2, 3};
      if (u < 90) v = f2b(W0[rowmap[k] * 90 + u]);
    } else if (k < 10) {
      int dd = k - 5;
      if (u < 90) {
        float c0 = ac[(o * 5 + dd) * 2 + 0], c1 = ac[(o * 5 + dd) * 2 + 1];
        v = f2b(b0[u] + c0 * W0[4 * 90 + u] + c1 * W0[6 * 90 + u]);
      } else if (u == 90) {
        v = (u16)0x3F80;  // the "1" unit
      }
    }
    W0f[i] = v;
  }
  for (int i = tid; i < 2 * 18 * 64 * 8; i += nth) {
    int which = i / (18 * 64 * 8);
    int j2 = i % (18 * 64 * 8);
    int jj = j2 & 7, lane = (j2 >> 3) & 63, f = j2 >> 9;
    int t = f / 3, ki = f % 3;
    int qA = lane >> 4, m = lane & 15;
    int row = 32 * ki + 16 * (jj >> 2) + 4 * qA + (jj & 3);
    int col = 16 * t + m;
    const float* W = which ? W2 : W1;
    const float* bb = which ? b2 : b1;
    u16 v = 0;
    if (row < 90 && col < 90) v = f2b(W[row * 90 + col]);
    else if (row == 90) v = (col < 90) ? f2b(bb[col]) : ((col == 90) ? (u16)0x3F80 : (u16)0);
    (which ? W2f : W1f)[j2] = v;
  }
}

__device__ __forceinline__ f32x4 mfma16(short8 a, short8 b, f32x4 c) {
  return __builtin_amdgcn_mfma_f32_16x16x32_bf16(a, b, c, 0, 0, 0);
}

__device__ __forceinline__ short8 packB(const f32x4& a0, const f32x4& a1) {
  union { u32 u[4]; short8 s; } fu;
  fu.u[0] = pk2(fmaxf(a0.x, 0.f), fmaxf(a0.y, 0.f));
  fu.u[1] = pk2(fmaxf(a0.z, 0.f), fmaxf(a0.w, 0.f));
  fu.u[2] = pk2(fmaxf(a1.x, 0.f), fmaxf(a1.y, 0.f));
  fu.u[3] = pk2(fmaxf(a1.z, 0.f), fmaxf(a1.w, 0.f));
  return fu.s;
}

// R13: R12's LDS-streamed residency + R10's dual-tile pairing. R12's counters
// showed the LDS read port at ~71% busy (36 b128/d-iter/wave x 1.94M total
// ~ 91k cyc/CU) — the new limiter. Two tiles per wave (pair {f, f+900}:
// same o, batch+4) make each streamed fragment read feed TWO MFMAs, halving
// per-tile LDS traffic (91k -> 45k cyc/CU) and doubling in-wave ILP.
// Low-register regime is preserved (~110 peak VGPR < 128 = 4-wave cap).
__global__ __launch_bounds__(256, 4) void mlp_kernel(
    const float* __restrict__ x, const float* __restrict__ w3t,
    const u16* __restrict__ W0f, const u16* __restrict__ W1f,
    const u16* __restrict__ W2f, float* __restrict__ out) {
  __shared__ short8 ldsW1[18 * 64];  // 18432 B
  __shared__ short8 ldsW2[18 * 64];  // 18432 B
  __shared__ float ldsW3[96];        // 384 B  => 37248 B, 4 blocks/CU
  const int tid = threadIdx.x;
  const int o = blockIdx.x % 6;    // block's output channel
  const int bi = blockIdx.x / 6;   // 0..224
  {  // cooperative one-time fill
    const uint4* s1 = (const uint4*)W1f;
    const uint4* s2 = (const uint4*)W2f;
    uint4* d1 = (uint4*)ldsW1;
    uint4* d2 = (uint4*)ldsW2;
#pragma unroll
    for (int i = 0; i < 5; ++i) {
      int j = tid + i * 256;
      if (j < 1152) { d1[j] = s1[j]; d2[j] = s2[j]; }
    }
    if (tid < 96) ldsW3[tid] = w3t[tid];
  }
  __syncthreads();  // only barrier; LDS read-only afterwards

  const int lane = tid & 63;
  const int wv = tid >> 6;
  const int q = lane >> 4, n = lane & 15;

  // resident o-specific L1 fragments (24 VGPRs)
  short8 w0f[6];
  const short8* p0 = (const short8*)W0f + o * 384;
#pragma unroll
  for (int t = 0; t < 6; ++t) w0f[t] = p0[t * 64 + lane];

  // wave's pair: f in 0..899 within o -> tiles (bb, idx) and (bb+4, idx)
  const int f = bi * 4 + wv;           // 0..899
  const int bb = f / 225, idx = f % 225;
  const int seg0 = bb * 6 + o;
  const int l0 = idx * 16;
  const int l = l0 + n;
  const int oh = l / 60, ow = l - oh * 60;
  const float* xrow0 = x + (bb * 4096 + oh * 64 + ow);
  const float* xrow1 = xrow0 + 4 * 4096;  // batch +4

  const f32x4 z4 = {0.f, 0.f, 0.f, 0.f};
  float outAcc0 = 0.f, outAcc1 = 0.f;

  float pa0 = xrow0[0], pa1 = xrow0[1], pa2 = xrow0[2], pa3 = xrow0[3], pa4 = xrow0[4];
  float pb0 = xrow1[0], pb1 = xrow1[1], pb2 = xrow1[2], pb3 = xrow1[3], pb4 = xrow1[4];

#pragma unroll 1
  for (int d = 0; d < 5; ++d) {
    float a0 = pa0, a1 = pa1, a2 = pa2, a3 = pa3, a4 = pa4;
    float b0 = pb0, b1 = pb1, b2 = pb2, b3 = pb3, b4 = pb4;
    if (d < 4) {
      const float* xp0 = xrow0 + (d + 1) * 64;
      const float* xp1 = xrow1 + (d + 1) * 64;
      pa0 = xp0[0]; pa1 = xp0[1]; pa2 = xp0[2]; pa3 = xp0[3]; pa4 = xp0[4];
      pb0 = xp1[0]; pb1 = xp1[1]; pb2 = xp1[2]; pb3 = xp1[3]; pb4 = xp1[4];
    }

    // one-hot(d) bias-selector slots k=5..9 (wave-uniform -> SALU)
    const u32 u3c = (d == 1) ? 0x00003F80u : ((d == 2) ? 0x3F800000u : 0u);  // k6,k7
    const u32 q1c = (d == 3) ? 0x00003F80u : ((d == 4) ? 0x3F800000u : 0u);  // k8,k9
    const float k5f = (d == 0) ? 1.0f : 0.0f;                                // k5

    union { u32 u[4]; short8 s; } bu0, bu1;
    u32 ta = pk2(a0, a1), tb = pk2(b0, b1);
    bu0.u[0] = (q == 1) ? q1c : ta;
    bu1.u[0] = (q == 1) ? q1c : tb;
    bu0.u[1] = pk2(a2, a3);  bu1.u[1] = pk2(b2, b3);
    bu0.u[2] = pk2(a4, k5f); bu1.u[2] = pk2(b4, k5f);
    bu0.u[3] = u3c;          bu1.u[3] = u3c;
    short8 bx0 = bu0.s, bx1 = bu1.s;

    // ---- L1: chunk-of-2-t, both tiles, pack immediately
    short8 h0[3], h1[3];
#pragma unroll
    for (int c = 0; c < 3; ++c) {
      f32x4 v00 = mfma16(w0f[2 * c + 0], bx0, z4);
      f32x4 v01 = mfma16(w0f[2 * c + 1], bx0, z4);
      f32x4 v10 = mfma16(w0f[2 * c + 0], bx1, z4);
      f32x4 v11 = mfma16(w0f[2 * c + 1], bx1, z4);
      h0[c] = packB(v00, v01);
      h1[c] = packB(v10, v11);
    }

    // ---- L2 streamed: each fragment read feeds both tiles
    short8 g0[3], g1[3];
#pragma unroll
    for (int c = 0; c < 3; ++c) {
      lds_compiler_fence();
      const short8* pb = &ldsW1[c * 6 * 64 + lane];
      short8 f0 = pb[0 * 64], f1 = pb[1 * 64], f2 = pb[2 * 64];
      short8 f3 = pb[3 * 64], f4 = pb[4 * 64], f5 = pb[5 * 64];
      f32x4 v00 = mfma16(f0, h0[0], z4);
      f32x4 v10 = mfma16(f0, h1[0], z4);
      v00 = mfma16(f1, h0[1], v00);
      v10 = mfma16(f1, h1[1], v10);
      v00 = mfma16(f2, h0[2], v00);
      v10 = mfma16(f2, h1[2], v10);
      f32x4 v01 = mfma16(f3, h0[0], z4);
      f32x4 v11 = mfma16(f3, h1[0], z4);
      v01 = mfma16(f4, h0[1], v01);
      v11 = mfma16(f4, h1[1], v11);
      v01 = mfma16(f5, h0[2], v01);
      v11 = mfma16(f5, h1[2], v11);
      g0[c] = packB(v00, v01);
      g1[c] = packB(v10, v11);
    }

    // ---- L3 streamed + L4 dot (w3 reads shared by both tiles)
#pragma unroll
    for (int c = 0; c < 3; ++c) {
      lds_compiler_fence();
      const short8* pb = &ldsW2[c * 6 * 64 + lane];
      short8 f0 = pb[0 * 64], f1 = pb[1 * 64], f2 = pb[2 * 64];
      short8 f3 = pb[3 * 64], f4 = pb[4 * 64], f5 = pb[5 * 64];
      f32x4 v00 = mfma16(f0, g0[0], z4);
      f32x4 v10 = mfma16(f0, g1[0], z4);
      v00 = mfma16(f1, g0[1], v00);
      v10 = mfma16(f1, g1[1], v10);
      v00 = mfma16(f2, g0[2], v00);
      v10 = mfma16(f2, g1[2], v10);
      f32x4 v01 = mfma16(f3, g0[0], z4);
      f32x4 v11 = mfma16(f3, g1[0], z4);
      v01 = mfma16(f4, g0[1], v01);
      v11 = mfma16(f4, g1[1], v11);
      v01 = mfma16(f5, g0[2], v01);
      v11 = mfma16(f5, g1[2], v11);
      f32x4 w3a = *(const f32x4*)&ldsW3[(2 * c + 0) * 16 + q * 4];
      f32x4 w3b = *(const f32x4*)&ldsW3[(2 * c + 1) * 16 + q * 4];
      outAcc0 += fmaxf(v00.x, 0.f) * w3a.x + fmaxf(v00.y, 0.f) * w3a.y +
                 fmaxf(v00.z, 0.f) * w3a.z + fmaxf(v00.w, 0.f) * w3a.w;
      outAcc0 += fmaxf(v01.x, 0.f) * w3b.x + fmaxf(v01.y, 0.f) * w3b.y +
                 fmaxf(v01.z, 0.f) * w3b.z + fmaxf(v01.w, 0.f) * w3b.w;
      outAcc1 += fmaxf(v10.x, 0.f) * w3a.x + fmaxf(v10.y, 0.f) * w3a.y +
                 fmaxf(v10.z, 0.f) * w3a.z + fmaxf(v10.w, 0.f) * w3a.w;
      outAcc1 += fmaxf(v11.x, 0.f) * w3b.x + fmaxf(v11.y, 0.f) * w3b.y +
                 fmaxf(v11.z, 0.f) * w3b.z + fmaxf(v11.w, 0.f) * w3b.w;
    }
  }  // d

  // reduce quad-partials and store both tiles
  outAcc0 += __shfl_xor(outAcc0, 16, 64);
  outAcc0 += __shfl_xor(outAcc0, 32, 64);
  outAcc1 += __shfl_xor(outAcc1, 16, 64);
  outAcc1 += __shfl_xor(outAcc1, 32, 64);
  if (lane < 16) {
    out[seg0 * 3600 + l0 + lane] = outAcc0;
    out[(seg0 + 24) * 3600 + l0 + lane] = outAcc1;
  }
}

extern "C" void kernel_launch(void* const* d_in, const int* in_sizes, int n_in,
                              void* d_out, int out_size, void* d_ws, size_t ws_size,
                              hipStream_t stream) {
  const float* x  = (const float*)d_in[0];
  const float* ac = (const float*)d_in[1];
  const float* W0 = (const float*)d_in[2];
  const float* b0 = (const float*)d_in[3];
  const float* W1 = (const float*)d_in[4];
  const float* b1 = (const float*)d_in[5];
  const float* W2 = (const float*)d_in[6];
  const float* b2 = (const float*)d_in[7];
  const float* W3 = (const float*)d_in[8];
  const float* b3 = (const float*)d_in[9];
  float* out = (float*)d_out;
  char* ws = (char*)d_ws;
  float* w3t = (float*)(ws + WS_W3T);
  u16* W0f = (u16*)(ws + WS_W0F);
  u16* W1f = (u16*)(ws + WS_W1F);
  u16* W2f = (u16*)(ws + WS_W2F);
  prep_kernel<<<128, 256, 0, stream>>>(ac, W0, b0, W1, b1, W2, b2, W3, b3,
                                       w3t, W0f, W1f, W2f);
  mlp_kernel<<<1350, 256, 0, stream>>>(x, w3t, W0f, W1f, W2f, out);
}

// Round 14
// 114.717 us; speedup vs baseline: 1.0639x; 1.0639x over previous
//
#include <hip/hip_runtime.h>

typedef unsigned short u16;
typedef unsigned int u32;
typedef __attribute__((ext_vector_type(8))) short short8;   // 8 bf16 (4 VGPRs)
typedef __attribute__((ext_vector_type(4))) float f32x4;

// ws layout (bytes), all 16B-aligned
#define WS_W3T  0        // float[96]  (W3 augmented: [90]=b3, [91..95]=0)
#define WS_W0F  384      // u16[6][6*64*8]  per-o L1 fragments w/ bias rows k=5..9
#define WS_W1F  37248    // u16[18*64*8]
#define WS_W2F  55680    // u16[18*64*8]   (ends 74112)

__device__ __forceinline__ u16 f2b(float f) {  // RNE f32 -> bf16 (prep only)
  union { u32 i; float f; } v; v.f = f;
  u32 i = v.i;
  return (u16)((i + 0x7FFFu + ((i >> 16) & 1u)) >> 16);
}

// 3-op bf16 pair pack (round-half-up + v_perm). Verified R7.
__device__ __forceinline__ u32 pk2(float a, float b) {  // a -> low, b -> high
  u32 ia = __float_as_uint(a) + 0x8000u;
  u32 ib = __float_as_uint(b) + 0x8000u;
  return __builtin_amdgcn_perm(ib, ia, 0x07060302u);
}

// Compiler-only memory barrier: pins ds_reads into their chunks.
__device__ __forceinline__ void lds_compiler_fence() {
  asm volatile("" ::: "memory");
}

// prep: identical math to R8-R13 (verified absmax 7.8e-3).
__global__ void prep_kernel(const float* __restrict__ ac, const float* __restrict__ W0,
                            const float* __restrict__ b0, const float* __restrict__ W1,
                            const float* __restrict__ b1, const float* __restrict__ W2,
                            const float* __restrict__ b2, const float* __restrict__ W3,
                            const float* __restrict__ b3,
                            float* __restrict__ w3t, u16* __restrict__ W0f,
                            u16* __restrict__ W1f, u16* __restrict__ W2f) {
  int tid = blockIdx.x * blockDim.x + threadIdx.x;
  int nth = gridDim.x * blockDim.x;
  for (int i = tid; i < 96; i += nth)
    w3t[i] = (i < 90) ? W3[i] : ((i == 90) ? b3[0] : 0.0f);
  for (int i = tid; i < 6 * 6 * 64 * 8; i += nth) {
    int o = i / 3072, rem = i % 3072;
    int t = rem >> 9, lane = (rem >> 3) & 63, jj = rem & 7;
    int q = lane >> 4, m = lane & 15;
    int k = q * 8 + jj;
    int u = t * 16 + m;
    u16 v = 0;
    if (k < 5) {
      const int rowmap[5] = {5, 0, 1, 2, 3};
      if (u < 90) v = f2b(W0[rowmap[k] * 90 + u]);
    } else if (k < 10) {
      int dd = k - 5;
      if (u < 90) {
        float c0 = ac[(o * 5 + dd) * 2 + 0], c1 = ac[(o * 5 + dd) * 2 + 1];
        v = f2b(b0[u] + c0 * W0[4 * 90 + u] + c1 * W0[6 * 90 + u]);
      } else if (u == 90) {
        v = (u16)0x3F80;  // the "1" unit
      }
    }
    W0f[i] = v;
  }
  for (int i = tid; i < 2 * 18 * 64 * 8; i += nth) {
    int which = i / (18 * 64 * 8);
    int j2 = i % (18 * 64 * 8);
    int jj = j2 & 7, lane = (j2 >> 3) & 63, f = j2 >> 9;
    int t = f / 3, ki = f % 3;
    int qA = lane >> 4, m = lane & 15;
    int row = 32 * ki + 16 * (jj >> 2) + 4 * qA + (jj & 3);
    int col = 16 * t + m;
    const float* W = which ? W2 : W1;
    const float* bb = which ? b2 : b1;
    u16 v = 0;
    if (row < 90 && col < 90) v = f2b(W[row * 90 + col]);
    else if (row == 90) v = (col < 90) ? f2b(bb[col]) : ((col == 90) ? (u16)0x3F80 : (u16)0);
    (which ? W2f : W1f)[j2] = v;
  }
}

__device__ __forceinline__ f32x4 mfma16(short8 a, short8 b, f32x4 c) {
  return __builtin_amdgcn_mfma_f32_16x16x32_bf16(a, b, c, 0, 0, 0);
}

__device__ __forceinline__ short8 packB(const f32x4& a0, const f32x4& a1) {
  union { u32 u[4]; short8 s; } fu;
  fu.u[0] = pk2(fmaxf(a0.x, 0.f), fmaxf(a0.y, 0.f));
  fu.u[1] = pk2(fmaxf(a0.z, 0.f), fmaxf(a0.w, 0.f));
  fu.u[2] = pk2(fmaxf(a1.x, 0.f), fmaxf(a1.y, 0.f));
  fu.u[3] = pk2(fmaxf(a1.z, 0.f), fmaxf(a1.w, 0.f));
  return fu.s;
}

// R14 = R13 dual-tile LDS-sharing, fixed: __launch_bounds__(256,3) (170-reg
// cap — R13's (256,4)/128 cap spilled 25 MB to scratch, the canary that
// explained its regression) and w3 back in registers (24 regs, kills the
// last 6 shared LDS reads). Per-tile LDS traffic: R12 42 b128 -> 18 b128
// (46k cyc/CU vs measured 106k = 83% port busy at R12) — the port drops
// below the MFMA pipe as limiter.
__global__ __launch_bounds__(256, 3) void mlp_kernel(
    const float* __restrict__ x, const float* __restrict__ w3t,
    const u16* __restrict__ W0f, const u16* __restrict__ W1f,
    const u16* __restrict__ W2f, float* __restrict__ out) {
  __shared__ short8 ldsW1[18 * 64];  // 18432 B
  __shared__ short8 ldsW2[18 * 64];  // 18432 B => 36864 B, 4 blocks/CU by LDS
  const int tid = threadIdx.x;
  const int o = blockIdx.x % 6;    // block's output channel
  const int bi = blockIdx.x / 6;   // 0..224
  {  // cooperative one-time fill
    const uint4* s1 = (const uint4*)W1f;
    const uint4* s2 = (const uint4*)W2f;
    uint4* d1 = (uint4*)ldsW1;
    uint4* d2 = (uint4*)ldsW2;
#pragma unroll
    for (int i = 0; i < 5; ++i) {
      int j = tid + i * 256;
      if (j < 1152) { d1[j] = s1[j]; d2[j] = s2[j]; }
    }
  }
  __syncthreads();  // only barrier; LDS read-only afterwards

  const int lane = tid & 63;
  const int wv = tid >> 6;
  const int q = lane >> 4, n = lane & 15;

  // resident o-specific L1 fragments (24 VGPRs) + augmented W3 (24 VGPRs)
  short8 w0f[6];
  const short8* p0 = (const short8*)W0f + o * 384;
#pragma unroll
  for (int t = 0; t < 6; ++t) w0f[t] = p0[t * 64 + lane];
  f32x4 w3v[6];
#pragma unroll
  for (int t = 0; t < 6; ++t) w3v[t] = *(const f32x4*)(w3t + t * 16 + q * 4);

  // wave's pair: f in 0..899 within o -> tiles (bb, idx) and (bb+4, idx)
  const int f = bi * 4 + wv;           // 0..899
  const int bb = f / 225, idx = f % 225;
  const int seg0 = bb * 6 + o;
  const int l0 = idx * 16;
  const int l = l0 + n;
  const int oh = l / 60, ow = l - oh * 60;
  const float* xrow0 = x + (bb * 4096 + oh * 64 + ow);
  const float* xrow1 = xrow0 + 4 * 4096;  // batch +4

  const f32x4 z4 = {0.f, 0.f, 0.f, 0.f};
  float outAcc0 = 0.f, outAcc1 = 0.f;

  float pa0 = xrow0[0], pa1 = xrow0[1], pa2 = xrow0[2], pa3 = xrow0[3], pa4 = xrow0[4];
  float pb0 = xrow1[0], pb1 = xrow1[1], pb2 = xrow1[2], pb3 = xrow1[3], pb4 = xrow1[4];

#pragma unroll 1
  for (int d = 0; d < 5; ++d) {
    float a0 = pa0, a1 = pa1, a2 = pa2, a3 = pa3, a4 = pa4;
    float b0 = pb0, b1 = pb1, b2 = pb2, b3 = pb3, b4 = pb4;
    if (d < 4) {
      const float* xp0 = xrow0 + (d + 1) * 64;
      const float* xp1 = xrow1 + (d + 1) * 64;
      pa0 = xp0[0]; pa1 = xp0[1]; pa2 = xp0[2]; pa3 = xp0[3]; pa4 = xp0[4];
      pb0 = xp1[0]; pb1 = xp1[1]; pb2 = xp1[2]; pb3 = xp1[3]; pb4 = xp1[4];
    }

    // one-hot(d) bias-selector slots k=5..9 (wave-uniform -> SALU)
    const u32 u3c = (d == 1) ? 0x00003F80u : ((d == 2) ? 0x3F800000u : 0u);  // k6,k7
    const u32 q1c = (d == 3) ? 0x00003F80u : ((d == 4) ? 0x3F800000u : 0u);  // k8,k9
    const float k5f = (d == 0) ? 1.0f : 0.0f;                                // k5

    union { u32 u[4]; short8 s; } bu0, bu1;
    u32 ta = pk2(a0, a1), tb = pk2(b0, b1);
    bu0.u[0] = (q == 1) ? q1c : ta;
    bu1.u[0] = (q == 1) ? q1c : tb;
    bu0.u[1] = pk2(a2, a3);  bu1.u[1] = pk2(b2, b3);
    bu0.u[2] = pk2(a4, k5f); bu1.u[2] = pk2(b4, k5f);
    bu0.u[3] = u3c;          bu1.u[3] = u3c;
    short8 bx0 = bu0.s, bx1 = bu1.s;

    // ---- L1: chunk-of-2-t, both tiles, pack immediately
    short8 h0[3], h1[3];
#pragma unroll
    for (int c = 0; c < 3; ++c) {
      f32x4 v00 = mfma16(w0f[2 * c + 0], bx0, z4);
      f32x4 v01 = mfma16(w0f[2 * c + 1], bx0, z4);
      f32x4 v10 = mfma16(w0f[2 * c + 0], bx1, z4);
      f32x4 v11 = mfma16(w0f[2 * c + 1], bx1, z4);
      h0[c] = packB(v00, v01);
      h1[c] = packB(v10, v11);
    }

    // ---- L2 streamed: each fragment read feeds both tiles
    short8 g0[3], g1[3];
#pragma unroll
    for (int c = 0; c < 3; ++c) {
      lds_compiler_fence();
      const short8* pb = &ldsW1[c * 6 * 64 + lane];
      short8 f0 = pb[0 * 64], f1 = pb[1 * 64], f2 = pb[2 * 64];
      short8 f3 = pb[3 * 64], f4 = pb[4 * 64], f5 = pb[5 * 64];
      f32x4 v00 = mfma16(f0, h0[0], z4);
      f32x4 v10 = mfma16(f0, h1[0], z4);
      v00 = mfma16(f1, h0[1], v00);
      v10 = mfma16(f1, h1[1], v10);
      v00 = mfma16(f2, h0[2], v00);
      v10 = mfma16(f2, h1[2], v10);
      f32x4 v01 = mfma16(f3, h0[0], z4);
      f32x4 v11 = mfma16(f3, h1[0], z4);
      v01 = mfma16(f4, h0[1], v01);
      v11 = mfma16(f4, h1[1], v11);
      v01 = mfma16(f5, h0[2], v01);
      v11 = mfma16(f5, h1[2], v11);
      g0[c] = packB(v00, v01);
      g1[c] = packB(v10, v11);
    }

    // ---- L3 streamed + L4 dot with resident w3v
#pragma unroll
    for (int c = 0; c < 3; ++c) {
      lds_compiler_fence();
      const short8* pb = &ldsW2[c * 6 * 64 + lane];
      short8 f0 = pb[0 * 64], f1 = pb[1 * 64], f2 = pb[2 * 64];
      short8 f3 = pb[3 * 64], f4 = pb[4 * 64], f5 = pb[5 * 64];
      f32x4 v00 = mfma16(f0, g0[0], z4);
      f32x4 v10 = mfma16(f0, g1[0], z4);
      v00 = mfma16(f1, g0[1], v00);
      v10 = mfma16(f1, g1[1], v10);
      v00 = mfma16(f2, g0[2], v00);
      v10 = mfma16(f2, g1[2], v10);
      f32x4 v01 = mfma16(f3, g0[0], z4);
      f32x4 v11 = mfma16(f3, g1[0], z4);
      v01 = mfma16(f4, g0[1], v01);
      v11 = mfma16(f4, g1[1], v11);
      v01 = mfma16(f5, g0[2], v01);
      v11 = mfma16(f5, g1[2], v11);
      f32x4 w3a = w3v[2 * c + 0];
      f32x4 w3b = w3v[2 * c + 1];
      outAcc0 += fmaxf(v00.x, 0.f) * w3a.x + fmaxf(v00.y, 0.f) * w3a.y +
                 fmaxf(v00.z, 0.f) * w3a.z + fmaxf(v00.w, 0.f) * w3a.w;
      outAcc0 += fmaxf(v01.x, 0.f) * w3b.x + fmaxf(v01.y, 0.f) * w3b.y +
                 fmaxf(v01.z, 0.f) * w3b.z + fmaxf(v01.w, 0.f) * w3b.w;
      outAcc1 += fmaxf(v10.x, 0.f) * w3a.x + fmaxf(v10.y, 0.f) * w3a.y +
                 fmaxf(v10.z, 0.f) * w3a.z + fmaxf(v10.w, 0.f) * w3a.w;
      outAcc1 += fmaxf(v11.x, 0.f) * w3b.x + fmaxf(v11.y, 0.f) * w3b.y +
                 fmaxf(v11.z, 0.f) * w3b.z + fmaxf(v11.w, 0.f) * w3b.w;
    }
  }  // d

  // reduce quad-partials and store both tiles
  outAcc0 += __shfl_xor(outAcc0, 16, 64);
  outAcc0 += __shfl_xor(outAcc0, 32, 64);
  outAcc1 += __shfl_xor(outAcc1, 16, 64);
  outAcc1 += __shfl_xor(outAcc1, 32, 64);
  if (lane < 16) {
    out[seg0 * 3600 + l0 + lane] = outAcc0;
    out[(seg0 + 24) * 3600 + l0 + lane] = outAcc1;
  }
}

extern "C" void kernel_launch(void* const* d_in, const int* in_sizes, int n_in,
                              void* d_out, int out_size, void* d_ws, size_t ws_size,
                              hipStream_t stream) {
  const float* x  = (const float*)d_in[0];
  const float* ac = (const float*)d_in[1];
  const float* W0 = (const float*)d_in[2];
  const float* b0 = (const float*)d_in[3];
  const float* W1 = (const float*)d_in[4];
  const float* b1 = (const float*)d_in[5];
  const float* W2 = (const float*)d_in[6];
  const float* b2 = (const float*)d_in[7];
  const float* W3 = (const float*)d_in[8];
  const float* b3 = (const float*)d_in[9];
  float* out = (float*)d_out;
  char* ws = (char*)d_ws;
  float* w3t = (float*)(ws + WS_W3T);
  u16* W0f = (u16*)(ws + WS_W0F);
  u16* W1f = (u16*)(ws + WS_W1F);
  u16* W2f = (u16*)(ws + WS_W2F);
  prep_kernel<<<128, 256, 0, stream>>>(ac, W0, b0, W1, b1, W2, b2, W3, b3,
                                       w3t, W0f, W1f, W2f);
  mlp_kernel<<<1350, 256, 0, stream>>>(x, w3t, W0f, W1f, W2f, out);
}